// Round 6
// baseline (396.031 us; speedup 1.0000x reference)
//
#include <hip/hip_runtime.h>

typedef short bf16x8 __attribute__((ext_vector_type(8)));
typedef float f32x4 __attribute__((ext_vector_type(4)));

#define MASK_NEG (-1e30f)

__device__ __forceinline__ unsigned short f2bf(float f) {
  union { float f; unsigned u; } v; v.f = f;
  unsigned r = v.u + 0x7fffu + ((v.u >> 16) & 1u);
  return (unsigned short)(r >> 16);
}

__device__ __forceinline__ float bf2f(unsigned short u) {
  union { unsigned u; float f; } v; v.u = ((unsigned)u) << 16;
  return v.f;
}

__device__ __forceinline__ void gl_lds16(const void* g, void* l) {
  __builtin_amdgcn_global_load_lds(
      (__attribute__((address_space(1))) void*)(void*)g,
      (__attribute__((address_space(3))) void*)l, 16, 0, 0);
}

// -------- transpose + fp32->bf16 convert: dst[c][r] = src[r][c] --------
__global__ __launch_bounds__(256) void transpose_f32_bf16(
    const float* __restrict__ src, unsigned short* __restrict__ dst,
    int R, int C, long sstride, long dstride) {
  __shared__ float tile[64][65];
  const int z = blockIdx.z;
  const float* s = src + (size_t)z * sstride;
  unsigned short* d = dst + (size_t)z * dstride;
  const int x0 = blockIdx.x * 64;   // src col base
  const int y0 = blockIdx.y * 64;   // src row base
  const int t = threadIdx.x;
  {
    const int r = t >> 4, c4 = (t & 15) * 4;
    for (int it = 0; it < 4; ++it) {
      const int rr = r + it * 16;
      const float4 v = *(const float4*)(s + (size_t)(y0 + rr) * C + x0 + c4);
      tile[rr][c4 + 0] = v.x; tile[rr][c4 + 1] = v.y;
      tile[rr][c4 + 2] = v.z; tile[rr][c4 + 3] = v.w;
    }
  }
  __syncthreads();
  {
    const int cc = t >> 4, r4 = (t & 15) * 4;
    for (int it = 0; it < 4; ++it) {
      const int c = cc + it * 16;
      ushort4 o;
      o.x = f2bf(tile[r4 + 0][c]); o.y = f2bf(tile[r4 + 1][c]);
      o.z = f2bf(tile[r4 + 2][c]); o.w = f2bf(tile[r4 + 3][c]);
      *(ushort4*)(d + (size_t)(x0 + c) * R + y0 + r4) = o;
    }
  }
}

// -------- generic bf16 MFMA GEMM (m97 LDS staging, scatter epilogue) --------
// C[M,N] = scale * A[M,K] * B[N,K]^T ; A,B K-contiguous.
template<bool F32OUT>
__global__ __launch_bounds__(256) void gemm_tn(
    const unsigned short* __restrict__ A, const unsigned short* __restrict__ B,
    void* __restrict__ Cv,
    int K, int ldA, int ldB, int ldC, float scale,
    long sAl, long sAb, long sAh,
    long sBl, long sBb, long sBh,
    long sCl, long sCb, long sCh,
    int zbase, int zdiv)
{
  __shared__ unsigned short As[4096];  // [128 rows][32 k] bf16, chunk-swizzled
  __shared__ unsigned short Bs[4096];
  const int z = blockIdx.z;
  const int g = zbase + z;
  const int gb = g / zdiv, gh = g % zdiv;
  const unsigned short* Ab = A + (size_t)z * sAl + (size_t)gb * sAb + (size_t)gh * sAh;
  const unsigned short* Bb = B + (size_t)z * sBl + (size_t)gb * sBb + (size_t)gh * sBh;
  const int m0 = blockIdx.y * 128, n0 = blockIdx.x * 128;
  const int t = threadIdx.x;
  const int lane = t & 63;
  const int wave = t >> 6;
  const int wm = wave >> 1, wn = wave & 1;

  const int sr = t >> 2;
  const int ss = t & 3;
  const int sq = ss ^ (sr & 3) ^ ((sr >> 2) & 3);

  const unsigned short* ap0 = Ab + (size_t)(m0 + sr) * ldA + sq * 8;
  const unsigned short* ap1 = Ab + (size_t)(m0 + sr + 64) * ldA + sq * 8;
  const unsigned short* bp0 = Bb + (size_t)(n0 + sr) * ldB + sq * 8;
  const unsigned short* bp1 = Bb + (size_t)(n0 + sr + 64) * ldB + sq * 8;

  char* asd0 = (char*)As + t * 16;
  char* asd1 = (char*)As + 4096 + t * 16;
  char* bsd0 = (char*)Bs + t * 16;
  char* bsd1 = (char*)Bs + 4096 + t * 16;

  const int tq = lane & 15, qd = lane >> 4;
  const int slot = qd ^ (tq & 3) ^ ((tq >> 2) & 3);

  f32x4 acc[4][4];
  #pragma unroll
  for (int i = 0; i < 4; ++i)
    #pragma unroll
    for (int j = 0; j < 4; ++j)
      acc[i][j] = f32x4{0.f, 0.f, 0.f, 0.f};

  const int kIters = K >> 5;
  for (int kt = 0; kt < kIters; ++kt) {
    __syncthreads();
    gl_lds16(ap0, asd0); gl_lds16(ap1, asd1);
    gl_lds16(bp0, bsd0); gl_lds16(bp1, bsd1);
    ap0 += 32; ap1 += 32; bp0 += 32; bp1 += 32;
    __builtin_amdgcn_s_waitcnt(0x0f70);    // vmcnt(0)
    __syncthreads();

    bf16x8 af[4], bfr[4];
    #pragma unroll
    for (int i = 0; i < 4; ++i)
      af[i] = *(const bf16x8*)(As + ((wm * 64 + i * 16 + tq) * 32 + slot * 8));
    #pragma unroll
    for (int j = 0; j < 4; ++j)
      bfr[j] = *(const bf16x8*)(Bs + ((wn * 64 + j * 16 + tq) * 32 + slot * 8));
    #pragma unroll
    for (int i = 0; i < 4; ++i)
      #pragma unroll
      for (int j = 0; j < 4; ++j)
        acc[i][j] = __builtin_amdgcn_mfma_f32_16x16x32_bf16(af[i], bfr[j], acc[i][j], 0, 0, 0);
  }

  const size_t cOff = (size_t)z * sCl + (size_t)gb * sCb + (size_t)gh * sCh;
  #pragma unroll
  for (int i = 0; i < 4; ++i) {
    const int row = m0 + wm * 64 + i * 16 + qd * 4;   // C/D: row=(lane>>4)*4+reg
    #pragma unroll
    for (int j = 0; j < 4; ++j) {
      const int col = n0 + wn * 64 + j * 16 + tq;     // C/D: col=lane&15
      if constexpr (F32OUT) {
        float* C = (float*)Cv + cOff;
        #pragma unroll
        for (int rr = 0; rr < 4; ++rr)
          C[(size_t)(row + rr) * ldC + col] = acc[i][j][rr] * scale;
      } else {
        unsigned short* C = (unsigned short*)Cv + cOff;
        #pragma unroll
        for (int rr = 0; rr < 4; ++rr)
          C[(size_t)(row + rr) * ldC + col] = f2bf(acc[i][j][rr] * scale);
      }
    }
  }
}

// -------- phase 1: colsum[bh][k] = sum_q exp(scale*Q.K^T + maskq - 20) ------
// QKV layout: [b][24 heads][l][128]; Q heads 0-7, K heads 8-15 (V 16-23).
__global__ __launch_bounds__(256) void colsum_pass(
    const unsigned short* __restrict__ QKV, float* __restrict__ colsum,
    const float* __restrict__ mask)
{
  __shared__ unsigned short As[4096];
  __shared__ unsigned short Bs[4096];
  const int g = blockIdx.z;
  const int b = g >> 3, h = g & 7;
  const unsigned short* Ab = QKV + (size_t)b * 3145728 + (size_t)h * 131072;
  const unsigned short* Bb = Ab + 1048576;
  const int m0 = blockIdx.y * 128, n0 = blockIdx.x * 128;
  const int t = threadIdx.x;
  const int lane = t & 63;
  const int wave = t >> 6;
  const int wm = wave >> 1, wn = wave & 1;

  const int sr = t >> 2, ss = t & 3;
  const int sq = ss ^ (sr & 3) ^ ((sr >> 2) & 3);

  const unsigned short* ap0 = Ab + (size_t)(m0 + sr) * 128 + sq * 8;
  const unsigned short* ap1 = Ab + (size_t)(m0 + sr + 64) * 128 + sq * 8;
  const unsigned short* bp0 = Bb + (size_t)(n0 + sr) * 128 + sq * 8;
  const unsigned short* bp1 = Bb + (size_t)(n0 + sr + 64) * 128 + sq * 8;

  char* asd0 = (char*)As + t * 16;
  char* asd1 = (char*)As + 4096 + t * 16;
  char* bsd0 = (char*)Bs + t * 16;
  char* bsd1 = (char*)Bs + 4096 + t * 16;

  const int tq = lane & 15, qd = lane >> 4;
  const int slot = qd ^ (tq & 3) ^ ((tq >> 2) & 3);

  f32x4 acc[4][4];
  #pragma unroll
  for (int i = 0; i < 4; ++i)
    #pragma unroll
    for (int j = 0; j < 4; ++j)
      acc[i][j] = f32x4{0.f, 0.f, 0.f, 0.f};

  #pragma unroll
  for (int kt = 0; kt < 4; ++kt) {
    __syncthreads();
    gl_lds16(ap0, asd0); gl_lds16(ap1, asd1);
    gl_lds16(bp0, bsd0); gl_lds16(bp1, bsd1);
    ap0 += 32; ap1 += 32; bp0 += 32; bp1 += 32;
    __builtin_amdgcn_s_waitcnt(0x0f70);    // vmcnt(0)
    __syncthreads();

    bf16x8 af[4], bfr[4];
    #pragma unroll
    for (int i = 0; i < 4; ++i)
      af[i] = *(const bf16x8*)(As + ((wm * 64 + i * 16 + tq) * 32 + slot * 8));
    #pragma unroll
    for (int j = 0; j < 4; ++j)
      bfr[j] = *(const bf16x8*)(Bs + ((wn * 64 + j * 16 + tq) * 32 + slot * 8));
    #pragma unroll
    for (int i = 0; i < 4; ++i)
      #pragma unroll
      for (int j = 0; j < 4; ++j)
        acc[i][j] = __builtin_amdgcn_mfma_f32_16x16x32_bf16(af[i], bfr[j], acc[i][j], 0, 0, 0);
  }

  float* cs = colsum + (size_t)g * 1024;
  const float scl = 0.08838834764831845f;  // 1/sqrt(128)
  const float* mrow = mask + (size_t)b * 1024;

  float cp[4] = {0.f, 0.f, 0.f, 0.f};
  #pragma unroll
  for (int i = 0; i < 4; ++i) {
    const int row0 = m0 + wm * 64 + i * 16 + qd * 4;
    const float4 m4 = *(const float4*)(mrow + row0);
    const float aq[4] = {(1.f - m4.x) * MASK_NEG - 20.f, (1.f - m4.y) * MASK_NEG - 20.f,
                         (1.f - m4.z) * MASK_NEG - 20.f, (1.f - m4.w) * MASK_NEG - 20.f};
    #pragma unroll
    for (int rr = 0; rr < 4; ++rr)
      #pragma unroll
      for (int j = 0; j < 4; ++j)
        cp[j] += __expf(acc[i][j][rr] * scl + aq[rr]);
  }
  #pragma unroll
  for (int j = 0; j < 4; ++j) {
    float v = cp[j];
    v += __shfl_xor(v, 16, 64);
    v += __shfl_xor(v, 32, 64);
    if (qd == 0)
      atomicAdd(&cs[n0 + wn * 64 + j * 16 + tq], v);
  }
}

// -------- transpose V [l][dv] -> V' [dv][l], scaled by 1/colsum[l] --------
__global__ __launch_bounds__(256) void tvscale(
    const unsigned short* __restrict__ QKV, unsigned short* __restrict__ Vp,
    const float* __restrict__ colsum)
{
  __shared__ unsigned short tile[64][72];
  const int g = blockIdx.z;
  const int b = g >> 3, h = g & 7;
  const unsigned short* S = QKV + (size_t)b * 3145728 + (size_t)(16 + h) * 131072;
  unsigned short* D = Vp + (size_t)g * 131072;
  const float* cs = colsum + (size_t)g * 1024;
  const int l0 = blockIdx.x * 64;   // 16 tiles
  const int d0 = blockIdx.y * 64;   // 2 tiles
  const int t = threadIdx.x;
  {
    const int r = t >> 4, c4 = (t & 15) * 4;
    for (int it = 0; it < 4; ++it) {
      const int rr = r + it * 16;
      const ushort4 v = *(const ushort4*)(S + (size_t)(l0 + rr) * 128 + d0 + c4);
      *(ushort4*)&tile[rr][c4] = v;
    }
  }
  __syncthreads();
  {
    const int cc = t >> 4, r4 = (t & 15) * 4;
    const float4 c4v = *(const float4*)(cs + l0 + r4);
    for (int it = 0; it < 4; ++it) {
      const int c = cc + it * 16;   // dv
      ushort4 o;
      o.x = f2bf(bf2f(tile[r4 + 0][c]) / c4v.x);
      o.y = f2bf(bf2f(tile[r4 + 1][c]) / c4v.y);
      o.z = f2bf(bf2f(tile[r4 + 2][c]) / c4v.z);
      o.w = f2bf(bf2f(tile[r4 + 3][c]) / c4v.w);
      *(ushort4*)(D + (size_t)(d0 + c) * 1024 + l0 + r4) = o;
    }
  }
}

// -------- phase 2: fused attention, 64-q tiles, 1024 blocks ----------------
// Per block: head g, q-tile qt. Loop 8 k-tiles of 128:
//   S = Q.K^T (regs, Q re-read from L2) -> P=exp -> LDS -> O += P.V'
__global__ __launch_bounds__(256) void fused_attnv(
    const unsigned short* __restrict__ QKV, const unsigned short* __restrict__ V,
    unsigned short* __restrict__ H, const float* __restrict__ mask)
{
  __shared__ unsigned short Pt[64 * 136];
  const int lin = blockIdx.x;            // 0..1023
  const int xcd = lin & 7;
  const int idx = lin >> 3;              // 0..127
  const int g = (xcd << 3) | (idx & 7);  // head 0..63, XCD-affine
  const int qt = idx >> 3;               // 0..15
  const int b = g >> 3, h = g & 7;
  const unsigned short* Qb = QKV + (size_t)b * 3145728 + (size_t)h * 131072;
  const unsigned short* Kb = Qb + 1048576;
  const unsigned short* Vb = V + (size_t)g * 131072;    // [dv][k], ld=1024
  unsigned short* C = H + (size_t)b * 1048576 + h * 128;
  const int m0 = qt * 64;
  const int t = threadIdx.x;
  const int lane = t & 63;
  const int wave = t >> 6;
  const int wm = wave >> 1, wn = wave & 1;
  const int tq = lane & 15, qd = lane >> 4;

  const float scl = 0.08838834764831845f;  // 1/sqrt(128)
  const float* mrow = mask + (size_t)b * 1024;

  // mask add-terms (C-layout rows m0 + wm*32 + i*16 + qd*4 + rr)
  float aq[2][4];
  #pragma unroll
  for (int i = 0; i < 2; ++i) {
    const float4 m4 = *(const float4*)(mrow + m0 + wm * 32 + i * 16 + qd * 4);
    aq[i][0] = (1.f - m4.x) * MASK_NEG - 20.f;
    aq[i][1] = (1.f - m4.y) * MASK_NEG - 20.f;
    aq[i][2] = (1.f - m4.z) * MASK_NEG - 20.f;
    aq[i][3] = (1.f - m4.w) * MASK_NEG - 20.f;
  }

  f32x4 accO[2][4];
  #pragma unroll
  for (int i = 0; i < 2; ++i)
    #pragma unroll
    for (int j = 0; j < 4; ++j)
      accO[i][j] = f32x4{0.f, 0.f, 0.f, 0.f};

  for (int kt = 0; kt < 8; ++kt) {
    // ---- S: q rows [wm*32,+32), k cols [kt*128 + wn*64, +64) ----
    f32x4 accS[2][4];
    #pragma unroll
    for (int i = 0; i < 2; ++i)
      #pragma unroll
      for (int j = 0; j < 4; ++j)
        accS[i][j] = f32x4{0.f, 0.f, 0.f, 0.f};

    const unsigned short* Kt = Kb + (size_t)(kt * 128 + wn * 64) * 128;
    #pragma unroll
    for (int kq = 0; kq < 4; ++kq) {
      bf16x8 qf[2], kf[4];
      #pragma unroll
      for (int i = 0; i < 2; ++i)
        qf[i] = *(const bf16x8*)(Qb + (size_t)(m0 + wm * 32 + i * 16 + tq) * 128 + kq * 32 + qd * 8);
      #pragma unroll
      for (int j = 0; j < 4; ++j)
        kf[j] = *(const bf16x8*)(Kt + (size_t)(j * 16 + tq) * 128 + kq * 32 + qd * 8);
      #pragma unroll
      for (int i = 0; i < 2; ++i)
        #pragma unroll
        for (int j = 0; j < 4; ++j)
          accS[i][j] = __builtin_amdgcn_mfma_f32_16x16x32_bf16(qf[i], kf[j], accS[i][j], 0, 0, 0);
    }

    __syncthreads();   // previous k-tile's Pt readers are done
    #pragma unroll
    for (int i = 0; i < 2; ++i) {
      const int prow = wm * 32 + i * 16 + qd * 4;
      #pragma unroll
      for (int j = 0; j < 4; ++j) {
        const int pcol = wn * 64 + j * 16 + tq;
        #pragma unroll
        for (int rr = 0; rr < 4; ++rr)
          Pt[(prow + rr) * 136 + pcol] = f2bf(__expf(accS[i][j][rr] * scl + aq[i][rr]));
      }
    }
    __syncthreads();

    // ---- O += P . V'^T over this k-tile ----
    const unsigned short* Vt = Vb + (size_t)(wn * 64) * 1024 + kt * 128;
    #pragma unroll
    for (int kq = 0; kq < 4; ++kq) {
      bf16x8 pf[2], vf[4];
      #pragma unroll
      for (int i = 0; i < 2; ++i)
        pf[i] = *(const bf16x8*)(Pt + (wm * 32 + i * 16 + tq) * 136 + kq * 32 + qd * 8);
      #pragma unroll
      for (int j = 0; j < 4; ++j)
        vf[j] = *(const bf16x8*)(Vt + (size_t)(j * 16 + tq) * 1024 + kq * 32 + qd * 8);
      #pragma unroll
      for (int i = 0; i < 2; ++i)
        #pragma unroll
        for (int j = 0; j < 4; ++j)
          accO[i][j] = __builtin_amdgcn_mfma_f32_16x16x32_bf16(pf[i], vf[j], accO[i][j], 0, 0, 0);
    }
  }

  #pragma unroll
  for (int i = 0; i < 2; ++i) {
    const int row = m0 + wm * 32 + i * 16 + qd * 4;
    #pragma unroll
    for (int j = 0; j < 4; ++j) {
      const int col = wn * 64 + j * 16 + tq;
      #pragma unroll
      for (int rr = 0; rr < 4; ++rr)
        C[(size_t)(row + rr) * 1024 + col] = f2bf(accO[i][j][rr]);
    }
  }
}

extern "C" void kernel_launch(void* const* d_in, const int* in_sizes, int n_in,
                              void* d_out, int out_size, void* d_ws, size_t ws_size,
                              hipStream_t stream) {
  const float* x    = (const float*)d_in[0];   // [8,1024,1024]  (B,D,L)
  const float* mask = (const float*)d_in[1];   // [8,1024]
  const float* Wq   = (const float*)d_in[2];   // [8,1024,128]
  const float* Wk   = (const float*)d_in[3];
  const float* Wv   = (const float*)d_in[4];
  const float* Wo   = (const float*)d_in[5];   // [1024,1024]
  float* out = (float*)d_out;                  // [8,1024,1024]  (B,D,L)

  char* p = (char*)d_ws;
  unsigned short* xt    = (unsigned short*)p; p += 16777216;  // [b][l][d] bf16
  unsigned short* WqkvT = (unsigned short*)p; p += 6291456;   // [24 heads][128][1024]
  unsigned short* Wot   = (unsigned short*)p; p += 2097152;   // [j][i]
  unsigned short* QKV   = (unsigned short*)p; p += 50331648;  // [b][24h][l][128]
  unsigned short* Vp    = (unsigned short*)p; p += 16777216;  // [b][h][dv][k]
  unsigned short* Hp    = (unsigned short*)p; p += 16777216;  // [b][l][h*128+dv]
  float* colsum = (float*)p; p += 262144;                     // [64][1024] fp32

  hipMemsetAsync(colsum, 0, 262144, stream);

  // prologue: transpose+convert
  transpose_f32_bf16<<<dim3(16, 16, 8), 256, 0, stream>>>(x,  xt,  1024, 1024, 1048576L, 1048576L);
  transpose_f32_bf16<<<dim3(2, 16, 8),  256, 0, stream>>>(Wq, WqkvT,           1024, 128, 131072L, 131072L);
  transpose_f32_bf16<<<dim3(2, 16, 8),  256, 0, stream>>>(Wk, WqkvT + 1048576, 1024, 128, 131072L, 131072L);
  transpose_f32_bf16<<<dim3(2, 16, 8),  256, 0, stream>>>(Wv, WqkvT + 2097152, 1024, 128, 131072L, 131072L);
  transpose_f32_bf16<<<dim3(16, 16, 1), 256, 0, stream>>>(Wo, Wot, 1024, 1024, 1048576L, 1048576L);

  // QKV[b][gh][l][dk] = xt[b] * WqkvT[gh]^T   (z=192: gb=b, gh=0..23)
  gemm_tn<false><<<dim3(1, 8, 192), 256, 0, stream>>>(
      xt, WqkvT, (void*)QKV, 1024, 1024, 1024, 128, 1.f,
      0L, 1048576L, 0L,  0L, 0L, 131072L,  0L, 3145728L, 131072L, 0, 24);

  // phase 1: colsum over q of exp-scores
  colsum_pass<<<dim3(8, 8, 64), 256, 0, stream>>>(QKV, colsum, mask);
  // V' = V^T / colsum (transpose fused with normalization)
  tvscale<<<dim3(16, 2, 64), 256, 0, stream>>>(QKV, Vp, colsum);
  // phase 2: fused S->exp->PV per (head, 64-row q-tile)
  fused_attnv<<<dim3(1024, 1, 1), 256, 0, stream>>>(QKV, Vp, Hp, mask);

  // out[b][j][l] = Wot[j,:] . H[b][l,:]   (M=1024 j, N=1024 l, K=1024 i)
  gemm_tn<true><<<dim3(8, 8, 8), 256, 0, stream>>>(
      Wot, Hp, (void*)out, 1024, 1024, 1024, 1024, 1.f,
      0L, 0L, 0L,  0L, 1048576L, 0L,  0L, 1048576L, 0L, 0, 1);
}

// Round 7
// 316.895 us; speedup vs baseline: 1.2497x; 1.2497x over previous
//
#include <hip/hip_runtime.h>

typedef short bf16x8 __attribute__((ext_vector_type(8)));
typedef float f32x4 __attribute__((ext_vector_type(4)));

#define MASK_NEG (-1e30f)

__device__ __forceinline__ unsigned short f2bf(float f) {
  union { float f; unsigned u; } v; v.f = f;
  unsigned r = v.u + 0x7fffu + ((v.u >> 16) & 1u);
  return (unsigned short)(r >> 16);
}

__device__ __forceinline__ float bf2f(unsigned short u) {
  union { unsigned u; float f; } v; v.u = ((unsigned)u) << 16;
  return v.f;
}

__device__ __forceinline__ void gl_lds16(const void* g, void* l) {
  __builtin_amdgcn_global_load_lds(
      (__attribute__((address_space(1))) void*)(void*)g,
      (__attribute__((address_space(3))) void*)l, 16, 0, 0);
}

// -------- transpose + fp32->bf16 convert: dst[c][r] = src[r][c] --------
__global__ __launch_bounds__(256) void transpose_f32_bf16(
    const float* __restrict__ src, unsigned short* __restrict__ dst,
    int R, int C, long sstride, long dstride) {
  __shared__ float tile[64][65];
  const int z = blockIdx.z;
  const float* s = src + (size_t)z * sstride;
  unsigned short* d = dst + (size_t)z * dstride;
  const int x0 = blockIdx.x * 64;   // src col base
  const int y0 = blockIdx.y * 64;   // src row base
  const int t = threadIdx.x;
  {
    const int r = t >> 4, c4 = (t & 15) * 4;
    for (int it = 0; it < 4; ++it) {
      const int rr = r + it * 16;
      const float4 v = *(const float4*)(s + (size_t)(y0 + rr) * C + x0 + c4);
      tile[rr][c4 + 0] = v.x; tile[rr][c4 + 1] = v.y;
      tile[rr][c4 + 2] = v.z; tile[rr][c4 + 3] = v.w;
    }
  }
  __syncthreads();
  {
    const int cc = t >> 4, r4 = (t & 15) * 4;
    for (int it = 0; it < 4; ++it) {
      const int c = cc + it * 16;
      ushort4 o;
      o.x = f2bf(tile[r4 + 0][c]); o.y = f2bf(tile[r4 + 1][c]);
      o.z = f2bf(tile[r4 + 2][c]); o.w = f2bf(tile[r4 + 3][c]);
      *(ushort4*)(d + (size_t)(x0 + c) * R + y0 + r4) = o;
    }
  }
}

// -------- generic bf16 MFMA GEMM (m97 LDS staging, scatter epilogue) --------
// C[M,N] = scale * A[M,K] * B[N,K]^T ; A,B K-contiguous.
template<bool F32OUT>
__global__ __launch_bounds__(256) void gemm_tn(
    const unsigned short* __restrict__ A, const unsigned short* __restrict__ B,
    void* __restrict__ Cv,
    int K, int ldA, int ldB, int ldC, float scale,
    long sAl, long sAb, long sAh,
    long sBl, long sBb, long sBh,
    long sCl, long sCb, long sCh,
    int zbase, int zdiv)
{
  __shared__ unsigned short As[4096];  // [128 rows][32 k] bf16, chunk-swizzled
  __shared__ unsigned short Bs[4096];
  const int z = blockIdx.z;
  const int g = zbase + z;
  const int gb = g / zdiv, gh = g % zdiv;
  const unsigned short* Ab = A + (size_t)z * sAl + (size_t)gb * sAb + (size_t)gh * sAh;
  const unsigned short* Bb = B + (size_t)z * sBl + (size_t)gb * sBb + (size_t)gh * sBh;
  const int m0 = blockIdx.y * 128, n0 = blockIdx.x * 128;
  const int t = threadIdx.x;
  const int lane = t & 63;
  const int wave = t >> 6;
  const int wm = wave >> 1, wn = wave & 1;

  const int sr = t >> 2;
  const int ss = t & 3;
  const int sq = ss ^ (sr & 3) ^ ((sr >> 2) & 3);

  const unsigned short* ap0 = Ab + (size_t)(m0 + sr) * ldA + sq * 8;
  const unsigned short* ap1 = Ab + (size_t)(m0 + sr + 64) * ldA + sq * 8;
  const unsigned short* bp0 = Bb + (size_t)(n0 + sr) * ldB + sq * 8;
  const unsigned short* bp1 = Bb + (size_t)(n0 + sr + 64) * ldB + sq * 8;

  char* asd0 = (char*)As + t * 16;
  char* asd1 = (char*)As + 4096 + t * 16;
  char* bsd0 = (char*)Bs + t * 16;
  char* bsd1 = (char*)Bs + 4096 + t * 16;

  const int tq = lane & 15, qd = lane >> 4;
  const int slot = qd ^ (tq & 3) ^ ((tq >> 2) & 3);

  f32x4 acc[4][4];
  #pragma unroll
  for (int i = 0; i < 4; ++i)
    #pragma unroll
    for (int j = 0; j < 4; ++j)
      acc[i][j] = f32x4{0.f, 0.f, 0.f, 0.f};

  const int kIters = K >> 5;
  for (int kt = 0; kt < kIters; ++kt) {
    __syncthreads();
    gl_lds16(ap0, asd0); gl_lds16(ap1, asd1);
    gl_lds16(bp0, bsd0); gl_lds16(bp1, bsd1);
    ap0 += 32; ap1 += 32; bp0 += 32; bp1 += 32;
    __builtin_amdgcn_s_waitcnt(0x0f70);    // vmcnt(0)
    __syncthreads();

    bf16x8 af[4], bfr[4];
    #pragma unroll
    for (int i = 0; i < 4; ++i)
      af[i] = *(const bf16x8*)(As + ((wm * 64 + i * 16 + tq) * 32 + slot * 8));
    #pragma unroll
    for (int j = 0; j < 4; ++j)
      bfr[j] = *(const bf16x8*)(Bs + ((wn * 64 + j * 16 + tq) * 32 + slot * 8));
    #pragma unroll
    for (int i = 0; i < 4; ++i)
      #pragma unroll
      for (int j = 0; j < 4; ++j)
        acc[i][j] = __builtin_amdgcn_mfma_f32_16x16x32_bf16(af[i], bfr[j], acc[i][j], 0, 0, 0);
  }

  const size_t cOff = (size_t)z * sCl + (size_t)gb * sCb + (size_t)gh * sCh;
  #pragma unroll
  for (int i = 0; i < 4; ++i) {
    const int row = m0 + wm * 64 + i * 16 + qd * 4;   // C/D: row=(lane>>4)*4+reg
    #pragma unroll
    for (int j = 0; j < 4; ++j) {
      const int col = n0 + wn * 64 + j * 16 + tq;     // C/D: col=lane&15
      if constexpr (F32OUT) {
        float* C = (float*)Cv + cOff;
        #pragma unroll
        for (int rr = 0; rr < 4; ++rr)
          C[(size_t)(row + rr) * ldC + col] = acc[i][j][rr] * scale;
      } else {
        unsigned short* C = (unsigned short*)Cv + cOff;
        #pragma unroll
        for (int rr = 0; rr < 4; ++rr)
          C[(size_t)(row + rr) * ldC + col] = f2bf(acc[i][j][rr] * scale);
      }
    }
  }
}

// -------- scores GEMM with fused mask + exp + query-axis column sums --------
// E[q][k] = exp(scale*Q[q,:].K[k,:] + (1-mask[b,q])*NEG - 20), bf16, per bh.
// colsum[bh][k] += sum_q E (fp32 atomics). Round-2 structure (58 us measured),
// reading the merged QKV layout [b][24 heads][l][128] (Q: h, K: 8+h).
__global__ __launch_bounds__(256) void gemm_scores_fused(
    const unsigned short* __restrict__ QKV,
    unsigned short* __restrict__ E, float* __restrict__ colsum,
    const float* __restrict__ mask, int zbase)
{
  __shared__ unsigned short As[4096];
  __shared__ unsigned short Bs[4096];
  const int z = blockIdx.z;
  const int g = zbase + z;
  const int b = g >> 3, h = g & 7;
  const unsigned short* Ab = QKV + (size_t)b * 3145728 + (size_t)h * 131072;
  const unsigned short* Bb = Ab + 1048576;
  const int m0 = blockIdx.y * 128, n0 = blockIdx.x * 128;
  const int t = threadIdx.x;
  const int lane = t & 63;
  const int wave = t >> 6;
  const int wm = wave >> 1, wn = wave & 1;

  const int sr = t >> 2, ss = t & 3;
  const int sq = ss ^ (sr & 3) ^ ((sr >> 2) & 3);

  const unsigned short* ap0 = Ab + (size_t)(m0 + sr) * 128 + sq * 8;
  const unsigned short* ap1 = Ab + (size_t)(m0 + sr + 64) * 128 + sq * 8;
  const unsigned short* bp0 = Bb + (size_t)(n0 + sr) * 128 + sq * 8;
  const unsigned short* bp1 = Bb + (size_t)(n0 + sr + 64) * 128 + sq * 8;

  char* asd0 = (char*)As + t * 16;
  char* asd1 = (char*)As + 4096 + t * 16;
  char* bsd0 = (char*)Bs + t * 16;
  char* bsd1 = (char*)Bs + 4096 + t * 16;

  const int tq = lane & 15, qd = lane >> 4;
  const int slot = qd ^ (tq & 3) ^ ((tq >> 2) & 3);

  f32x4 acc[4][4];
  #pragma unroll
  for (int i = 0; i < 4; ++i)
    #pragma unroll
    for (int j = 0; j < 4; ++j)
      acc[i][j] = f32x4{0.f, 0.f, 0.f, 0.f};

  #pragma unroll
  for (int kt = 0; kt < 4; ++kt) {
    __syncthreads();
    gl_lds16(ap0, asd0); gl_lds16(ap1, asd1);
    gl_lds16(bp0, bsd0); gl_lds16(bp1, bsd1);
    ap0 += 32; ap1 += 32; bp0 += 32; bp1 += 32;
    __builtin_amdgcn_s_waitcnt(0x0f70);    // vmcnt(0)
    __syncthreads();

    bf16x8 af[4], bfr[4];
    #pragma unroll
    for (int i = 0; i < 4; ++i)
      af[i] = *(const bf16x8*)(As + ((wm * 64 + i * 16 + tq) * 32 + slot * 8));
    #pragma unroll
    for (int j = 0; j < 4; ++j)
      bfr[j] = *(const bf16x8*)(Bs + ((wn * 64 + j * 16 + tq) * 32 + slot * 8));
    #pragma unroll
    for (int i = 0; i < 4; ++i)
      #pragma unroll
      for (int j = 0; j < 4; ++j)
        acc[i][j] = __builtin_amdgcn_mfma_f32_16x16x32_bf16(af[i], bfr[j], acc[i][j], 0, 0, 0);
  }

  unsigned short* Ep = E + (size_t)z * 1048576;
  float* cs = colsum + (size_t)g * 1024;
  const float scl = 0.08838834764831845f;  // 1/sqrt(128)
  const float* mrow = mask + (size_t)b * 1024;

  float cp[4] = {0.f, 0.f, 0.f, 0.f};   // per-j partial column sums
  #pragma unroll
  for (int i = 0; i < 4; ++i) {
    const int row0 = m0 + wm * 64 + i * 16 + qd * 4;   // q index base
    const float4 m4 = *(const float4*)(mrow + row0);
    const float aq[4] = {(1.f - m4.x) * MASK_NEG - 20.f, (1.f - m4.y) * MASK_NEG - 20.f,
                         (1.f - m4.z) * MASK_NEG - 20.f, (1.f - m4.w) * MASK_NEG - 20.f};
    #pragma unroll
    for (int rr = 0; rr < 4; ++rr) {
      unsigned short* erow = Ep + (size_t)(row0 + rr) * 1024 + n0 + wn * 64 + tq;
      #pragma unroll
      for (int j = 0; j < 4; ++j) {
        const float e = __expf(acc[i][j][rr] * scl + aq[rr]);
        cp[j] += e;
        erow[j * 16] = f2bf(e);
      }
    }
  }
  #pragma unroll
  for (int j = 0; j < 4; ++j) {
    float v = cp[j];
    v += __shfl_xor(v, 16, 64);
    v += __shfl_xor(v, 32, 64);
    if (qd == 0)
      atomicAdd(&cs[n0 + wn * 64 + j * 16 + tq], v);
  }
}

// -------- transpose V [l][dv] -> V' [dv][l], scaled by 1/colsum[l] --------
__global__ __launch_bounds__(256) void tvscale(
    const unsigned short* __restrict__ QKV, unsigned short* __restrict__ Vp,
    const float* __restrict__ colsum, int zbase)
{
  __shared__ unsigned short tile[64][72];
  const int z = blockIdx.z;
  const int g = zbase + z;
  const int b = g >> 3, h = g & 7;
  const unsigned short* S = QKV + (size_t)b * 3145728 + (size_t)(16 + h) * 131072;
  unsigned short* D = Vp + (size_t)g * 131072;
  const float* cs = colsum + (size_t)g * 1024;
  const int l0 = blockIdx.x * 64;   // 16 tiles
  const int d0 = blockIdx.y * 64;   // 2 tiles
  const int t = threadIdx.x;
  {
    const int r = t >> 4, c4 = (t & 15) * 4;
    for (int it = 0; it < 4; ++it) {
      const int rr = r + it * 16;
      const ushort4 v = *(const ushort4*)(S + (size_t)(l0 + rr) * 128 + d0 + c4);
      *(ushort4*)&tile[rr][c4] = v;
    }
  }
  __syncthreads();
  {
    const int cc = t >> 4, r4 = (t & 15) * 4;
    const float4 c4v = *(const float4*)(cs + l0 + r4);
    for (int it = 0; it < 4; ++it) {
      const int c = cc + it * 16;   // dv
      ushort4 o;
      o.x = f2bf(bf2f(tile[r4 + 0][c]) / c4v.x);
      o.y = f2bf(bf2f(tile[r4 + 1][c]) / c4v.y);
      o.z = f2bf(bf2f(tile[r4 + 2][c]) / c4v.z);
      o.w = f2bf(bf2f(tile[r4 + 3][c]) / c4v.w);
      *(ushort4*)(D + (size_t)(d0 + c) * 1024 + l0 + r4) = o;
    }
  }
}

extern "C" void kernel_launch(void* const* d_in, const int* in_sizes, int n_in,
                              void* d_out, int out_size, void* d_ws, size_t ws_size,
                              hipStream_t stream) {
  const float* x    = (const float*)d_in[0];   // [8,1024,1024]  (B,D,L)
  const float* mask = (const float*)d_in[1];   // [8,1024]
  const float* Wq   = (const float*)d_in[2];   // [8,1024,128]
  const float* Wk   = (const float*)d_in[3];
  const float* Wv   = (const float*)d_in[4];
  const float* Wo   = (const float*)d_in[5];   // [1024,1024]
  float* out = (float*)d_out;                  // [8,1024,1024]  (B,D,L)

  char* p = (char*)d_ws;
  unsigned short* xt    = (unsigned short*)p; p += 16777216;  // [b][l][d] bf16
  unsigned short* WqkvT = (unsigned short*)p; p += 6291456;   // [24 heads][128][1024]
  unsigned short* Wot   = (unsigned short*)p; p += 2097152;   // [j][i]
  unsigned short* QKV   = (unsigned short*)p; p += 50331648;  // [b][24h][l][128]
  unsigned short* Vp    = (unsigned short*)p; p += 16777216;  // [b][h][dv][k]
  unsigned short* Hp    = (unsigned short*)p; p += 16777216;  // [b][l][h*128+dv]
  float* colsum = (float*)p; p += 262144;                     // [64][1024] fp32
  const size_t fixedBytes = (size_t)(p - (char*)d_ws);

  long nbh = 1;
  if (ws_size > fixedBytes) {
    nbh = (long)((ws_size - fixedBytes) / 2097152);
    if (nbh < 1) nbh = 1;
    if (nbh > 64) nbh = 64;
  }
  unsigned short* Ep = (unsigned short*)p;   // nbh x [q][k] bf16 (unnormalized exp)

  hipMemsetAsync(colsum, 0, 262144, stream);

  // prologue: transpose+convert
  transpose_f32_bf16<<<dim3(16, 16, 8), 256, 0, stream>>>(x,  xt,  1024, 1024, 1048576L, 1048576L);
  transpose_f32_bf16<<<dim3(2, 16, 8),  256, 0, stream>>>(Wq, WqkvT,           1024, 128, 131072L, 131072L);
  transpose_f32_bf16<<<dim3(2, 16, 8),  256, 0, stream>>>(Wk, WqkvT + 1048576, 1024, 128, 131072L, 131072L);
  transpose_f32_bf16<<<dim3(2, 16, 8),  256, 0, stream>>>(Wv, WqkvT + 2097152, 1024, 128, 131072L, 131072L);
  transpose_f32_bf16<<<dim3(16, 16, 1), 256, 0, stream>>>(Wo, Wot, 1024, 1024, 1048576L, 1048576L);

  // QKV[b][gh][l][dk] = xt[b] * WqkvT[gh]^T   (z=192: gb=b, gh=0..23; 1536 blocks)
  gemm_tn<false><<<dim3(1, 8, 192), 256, 0, stream>>>(
      xt, WqkvT, (void*)QKV, 1024, 1024, 1024, 128, 1.f,
      0L, 1048576L, 0L,  0L, 0L, 131072L,  0L, 3145728L, 131072L, 0, 24);

  for (int s0 = 0; s0 < 64; s0 += (int)nbh) {
    const int cnt = (int)(((64 - s0) < nbh) ? (64 - s0) : nbh);
    // E + colsum (round-2 structure, 58 us measured)
    gemm_scores_fused<<<dim3(8, 8, cnt), 256, 0, stream>>>(QKV, Ep, colsum, mask, s0);
    // V' = V^T / colsum (transpose fused with normalization)
    tvscale<<<dim3(16, 2, cnt), 256, 0, stream>>>(QKV, Vp, colsum, s0);
    // H[b][q][h*128+dv] = E[q,:] . V'[dv,:]   (M=1024 q, N=128 dv, K=1024 k)
    gemm_tn<false><<<dim3(1, 8, cnt), 256, 0, stream>>>(
        Ep, Vp, (void*)Hp, 1024, 1024, 1024, 1024, 1.f,
        1048576L, 0L, 0L,  0L, 1048576L, 131072L,  0L, 1048576L, 128L, s0, 8);
  }
  // out[b][j][l] = Wot[j,:] . H[b][l,:]   (M=1024 j, N=1024 l, K=1024 i)
  gemm_tn<true><<<dim3(8, 8, 8), 256, 0, stream>>>(
      Wot, Hp, (void*)out, 1024, 1024, 1024, 1024, 1.f,
      0L, 0L, 0L,  0L, 1048576L, 0L,  0L, 1048576L, 0L, 0, 1);
}

// Round 8
// 298.034 us; speedup vs baseline: 1.3288x; 1.0633x over previous
//
#include <hip/hip_runtime.h>

typedef short bf16x8 __attribute__((ext_vector_type(8)));
typedef float f32x4 __attribute__((ext_vector_type(4)));

#define MASK_NEG (-1e30f)

__device__ __forceinline__ unsigned short f2bf(float f) {
  union { float f; unsigned u; } v; v.f = f;
  unsigned r = v.u + 0x7fffu + ((v.u >> 16) & 1u);
  return (unsigned short)(r >> 16);
}

__device__ __forceinline__ float bf2f(unsigned short u) {
  union { unsigned u; float f; } v; v.u = ((unsigned)u) << 16;
  return v.f;
}

__device__ __forceinline__ void gl_lds16(const void* g, void* l) {
  __builtin_amdgcn_global_load_lds(
      (__attribute__((address_space(1))) void*)(void*)g,
      (__attribute__((address_space(3))) void*)l, 16, 0, 0);
}

// -------- shared transpose body: dst[c][r] = bf16(src[r][c]), 64x64 tile ----
__device__ __forceinline__ void transpose_tile(
    const float* __restrict__ s, unsigned short* __restrict__ d,
    int R, int C, int x0, int y0, int t, float tile[64][65]) {
  {
    const int r = t >> 4, c4 = (t & 15) * 4;
    for (int it = 0; it < 4; ++it) {
      const int rr = r + it * 16;
      const float4 v = *(const float4*)(s + (size_t)(y0 + rr) * C + x0 + c4);
      tile[rr][c4 + 0] = v.x; tile[rr][c4 + 1] = v.y;
      tile[rr][c4 + 2] = v.z; tile[rr][c4 + 3] = v.w;
    }
  }
  __syncthreads();
  {
    const int cc = t >> 4, r4 = (t & 15) * 4;
    for (int it = 0; it < 4; ++it) {
      const int c = cc + it * 16;
      ushort4 o;
      o.x = f2bf(tile[r4 + 0][c]); o.y = f2bf(tile[r4 + 1][c]);
      o.z = f2bf(tile[r4 + 2][c]); o.w = f2bf(tile[r4 + 3][c]);
      *(ushort4*)(d + (size_t)(x0 + c) * R + y0 + r4) = o;
    }
  }
}

// -------- transpose x (8 batches) + Wo, all 1024x1024, one dispatch --------
__global__ __launch_bounds__(256) void transpose_x_wo(
    const float* __restrict__ x, const float* __restrict__ Wo,
    unsigned short* __restrict__ xt, unsigned short* __restrict__ Wot) {
  __shared__ float tile[64][65];
  const int z = blockIdx.z;   // 0..7: x batch, 8: Wo
  const float* s = (z < 8) ? (x + (size_t)z * 1048576) : Wo;
  unsigned short* d = (z < 8) ? (xt + (size_t)z * 1048576) : Wot;
  transpose_tile(s, d, 1024, 1024, blockIdx.x * 64, blockIdx.y * 64,
                 threadIdx.x, tile);
}

// -------- transpose all 24 per-head W matrices (1024x128) in one dispatch ---
__global__ __launch_bounds__(256) void transpose_w24(
    const float* __restrict__ Wq, const float* __restrict__ Wk,
    const float* __restrict__ Wv, unsigned short* __restrict__ WqkvT) {
  __shared__ float tile[64][65];
  const int z = blockIdx.z;   // 0..23
  const int sel = z >> 3, h = z & 7;
  const float* base = (sel == 0) ? Wq : (sel == 1) ? Wk : Wv;
  const float* s = base + (size_t)h * 131072;
  unsigned short* d = WqkvT + (size_t)z * 131072;
  transpose_tile(s, d, 1024, 128, blockIdx.x * 64, blockIdx.y * 64,
                 threadIdx.x, tile);
}

// -------- generic bf16 MFMA GEMM, BK=64 (m97 staging, scatter epilogue) -----
// C[M,N] = scale * A[M,K] * B[N,K]^T ; A,B K-contiguous; K % 64 == 0.
template<bool F32OUT>
__global__ __launch_bounds__(256) void gemm_tn(
    const unsigned short* __restrict__ A, const unsigned short* __restrict__ B,
    void* __restrict__ Cv,
    int K, int ldA, int ldB, int ldC, float scale,
    long sAl, long sAb, long sAh,
    long sBl, long sBb, long sBh,
    long sCl, long sCb, long sCh,
    int zbase, int zdiv)
{
  __shared__ unsigned short As[128 * 64];   // [128 rows][64 k], chunk-swizzled
  __shared__ unsigned short Bs[128 * 64];
  const int z = blockIdx.z;
  const int g = zbase + z;
  const int gb = g / zdiv, gh = g % zdiv;
  const unsigned short* Ab = A + (size_t)z * sAl + (size_t)gb * sAb + (size_t)gh * sAh;
  const unsigned short* Bb = B + (size_t)z * sBl + (size_t)gb * sBb + (size_t)gh * sBh;
  const int m0 = blockIdx.y * 128, n0 = blockIdx.x * 128;
  const int t = threadIdx.x;
  const int lane = t & 63;
  const int wave = t >> 6;
  const int wm = wave >> 1, wn = wave & 1;

  // staging: thread t fetches one 16B chunk per 32-row group.
  // row = c*32 + (t>>3); dst slot ss8 = t&7; source chunk sq8 = ss8 ^ (row&7).
  const int sr2 = t >> 3;          // 0..31
  const int ss8 = t & 7;
  const int sq8 = ss8 ^ (sr2 & 7); // row&7 == sr2&7 (32 | 8)

  const unsigned short* ap0 = Ab + (size_t)(m0 +  0 + sr2) * ldA + sq8 * 8;
  const unsigned short* ap1 = Ab + (size_t)(m0 + 32 + sr2) * ldA + sq8 * 8;
  const unsigned short* ap2 = Ab + (size_t)(m0 + 64 + sr2) * ldA + sq8 * 8;
  const unsigned short* ap3 = Ab + (size_t)(m0 + 96 + sr2) * ldA + sq8 * 8;
  const unsigned short* bp0 = Bb + (size_t)(n0 +  0 + sr2) * ldB + sq8 * 8;
  const unsigned short* bp1 = Bb + (size_t)(n0 + 32 + sr2) * ldB + sq8 * 8;
  const unsigned short* bp2 = Bb + (size_t)(n0 + 64 + sr2) * ldB + sq8 * 8;
  const unsigned short* bp3 = Bb + (size_t)(n0 + 96 + sr2) * ldB + sq8 * 8;

  char* asd0 = (char*)As +     0 + t * 16;
  char* asd1 = (char*)As +  4096 + t * 16;
  char* asd2 = (char*)As +  8192 + t * 16;
  char* asd3 = (char*)As + 12288 + t * 16;
  char* bsd0 = (char*)Bs +     0 + t * 16;
  char* bsd1 = (char*)Bs +  4096 + t * 16;
  char* bsd2 = (char*)Bs +  8192 + t * 16;
  char* bsd3 = (char*)Bs + 12288 + t * 16;

  const int tq = lane & 15, qd = lane >> 4;

  f32x4 acc[4][4];
  #pragma unroll
  for (int i = 0; i < 4; ++i)
    #pragma unroll
    for (int j = 0; j < 4; ++j)
      acc[i][j] = f32x4{0.f, 0.f, 0.f, 0.f};

  const int kIters = K >> 6;
  for (int kt = 0; kt < kIters; ++kt) {
    __syncthreads();
    gl_lds16(ap0, asd0); gl_lds16(ap1, asd1);
    gl_lds16(ap2, asd2); gl_lds16(ap3, asd3);
    gl_lds16(bp0, bsd0); gl_lds16(bp1, bsd1);
    gl_lds16(bp2, bsd2); gl_lds16(bp3, bsd3);
    ap0 += 64; ap1 += 64; ap2 += 64; ap3 += 64;
    bp0 += 64; bp1 += 64; bp2 += 64; bp3 += 64;
    __builtin_amdgcn_s_waitcnt(0x0f70);    // vmcnt(0)
    __syncthreads();

    #pragma unroll
    for (int kk = 0; kk < 2; ++kk) {
      bf16x8 af[4], bfr[4];
      #pragma unroll
      for (int i = 0; i < 4; ++i) {
        const int R = wm * 64 + i * 16 + tq;
        const int slot = (kk * 4 + qd) ^ (R & 7);
        af[i] = *(const bf16x8*)(As + R * 64 + slot * 8);
      }
      #pragma unroll
      for (int j = 0; j < 4; ++j) {
        const int R = wn * 64 + j * 16 + tq;
        const int slot = (kk * 4 + qd) ^ (R & 7);
        bfr[j] = *(const bf16x8*)(Bs + R * 64 + slot * 8);
      }
      #pragma unroll
      for (int i = 0; i < 4; ++i)
        #pragma unroll
        for (int j = 0; j < 4; ++j)
          acc[i][j] = __builtin_amdgcn_mfma_f32_16x16x32_bf16(af[i], bfr[j], acc[i][j], 0, 0, 0);
    }
  }

  const size_t cOff = (size_t)z * sCl + (size_t)gb * sCb + (size_t)gh * sCh;
  #pragma unroll
  for (int i = 0; i < 4; ++i) {
    const int row = m0 + wm * 64 + i * 16 + qd * 4;   // C/D: row=(lane>>4)*4+reg
    #pragma unroll
    for (int j = 0; j < 4; ++j) {
      const int col = n0 + wn * 64 + j * 16 + tq;     // C/D: col=lane&15
      if constexpr (F32OUT) {
        float* C = (float*)Cv + cOff;
        #pragma unroll
        for (int rr = 0; rr < 4; ++rr)
          C[(size_t)(row + rr) * ldC + col] = acc[i][j][rr] * scale;
      } else {
        unsigned short* C = (unsigned short*)Cv + cOff;
        #pragma unroll
        for (int rr = 0; rr < 4; ++rr)
          C[(size_t)(row + rr) * ldC + col] = f2bf(acc[i][j][rr] * scale);
      }
    }
  }
}

// -------- scores GEMM with fused mask + exp + query-axis column sums --------
// E[q][k] = exp(scale*Q[q,:].K[k,:] + (1-mask[b,q])*NEG - 20), bf16, per bh.
// colsum[bh][k] += sum_q E (fp32 atomics). Round-2 structure (58 us measured).
__global__ __launch_bounds__(256) void gemm_scores_fused(
    const unsigned short* __restrict__ QKV,
    unsigned short* __restrict__ E, float* __restrict__ colsum,
    const float* __restrict__ mask, int zbase)
{
  __shared__ unsigned short As[4096];
  __shared__ unsigned short Bs[4096];
  const int z = blockIdx.z;
  const int g = zbase + z;
  const int b = g >> 3, h = g & 7;
  const unsigned short* Ab = QKV + (size_t)b * 3145728 + (size_t)h * 131072;
  const unsigned short* Bb = Ab + 1048576;
  const int m0 = blockIdx.y * 128, n0 = blockIdx.x * 128;
  const int t = threadIdx.x;
  const int lane = t & 63;
  const int wave = t >> 6;
  const int wm = wave >> 1, wn = wave & 1;

  const int sr = t >> 2, ss = t & 3;
  const int sq = ss ^ (sr & 3) ^ ((sr >> 2) & 3);

  const unsigned short* ap0 = Ab + (size_t)(m0 + sr) * 128 + sq * 8;
  const unsigned short* ap1 = Ab + (size_t)(m0 + sr + 64) * 128 + sq * 8;
  const unsigned short* bp0 = Bb + (size_t)(n0 + sr) * 128 + sq * 8;
  const unsigned short* bp1 = Bb + (size_t)(n0 + sr + 64) * 128 + sq * 8;

  char* asd0 = (char*)As + t * 16;
  char* asd1 = (char*)As + 4096 + t * 16;
  char* bsd0 = (char*)Bs + t * 16;
  char* bsd1 = (char*)Bs + 4096 + t * 16;

  const int tq = lane & 15, qd = lane >> 4;
  const int slot = qd ^ (tq & 3) ^ ((tq >> 2) & 3);

  f32x4 acc[4][4];
  #pragma unroll
  for (int i = 0; i < 4; ++i)
    #pragma unroll
    for (int j = 0; j < 4; ++j)
      acc[i][j] = f32x4{0.f, 0.f, 0.f, 0.f};

  #pragma unroll
  for (int kt = 0; kt < 4; ++kt) {
    __syncthreads();
    gl_lds16(ap0, asd0); gl_lds16(ap1, asd1);
    gl_lds16(bp0, bsd0); gl_lds16(bp1, bsd1);
    ap0 += 32; ap1 += 32; bp0 += 32; bp1 += 32;
    __builtin_amdgcn_s_waitcnt(0x0f70);    // vmcnt(0)
    __syncthreads();

    bf16x8 af[4], bfr[4];
    #pragma unroll
    for (int i = 0; i < 4; ++i)
      af[i] = *(const bf16x8*)(As + ((wm * 64 + i * 16 + tq) * 32 + slot * 8));
    #pragma unroll
    for (int j = 0; j < 4; ++j)
      bfr[j] = *(const bf16x8*)(Bs + ((wn * 64 + j * 16 + tq) * 32 + slot * 8));
    #pragma unroll
    for (int i = 0; i < 4; ++i)
      #pragma unroll
      for (int j = 0; j < 4; ++j)
        acc[i][j] = __builtin_amdgcn_mfma_f32_16x16x32_bf16(af[i], bfr[j], acc[i][j], 0, 0, 0);
  }

  unsigned short* Ep = E + (size_t)z * 1048576;
  float* cs = colsum + (size_t)g * 1024;
  const float scl = 0.08838834764831845f;  // 1/sqrt(128)
  const float* mrow = mask + (size_t)b * 1024;

  float cp[4] = {0.f, 0.f, 0.f, 0.f};   // per-j partial column sums
  #pragma unroll
  for (int i = 0; i < 4; ++i) {
    const int row0 = m0 + wm * 64 + i * 16 + qd * 4;   // q index base
    const float4 m4 = *(const float4*)(mrow + row0);
    const float aq[4] = {(1.f - m4.x) * MASK_NEG - 20.f, (1.f - m4.y) * MASK_NEG - 20.f,
                         (1.f - m4.z) * MASK_NEG - 20.f, (1.f - m4.w) * MASK_NEG - 20.f};
    #pragma unroll
    for (int rr = 0; rr < 4; ++rr) {
      unsigned short* erow = Ep + (size_t)(row0 + rr) * 1024 + n0 + wn * 64 + tq;
      #pragma unroll
      for (int j = 0; j < 4; ++j) {
        const float e = __expf(acc[i][j][rr] * scl + aq[rr]);
        cp[j] += e;
        erow[j * 16] = f2bf(e);
      }
    }
  }
  #pragma unroll
  for (int j = 0; j < 4; ++j) {
    float v = cp[j];
    v += __shfl_xor(v, 16, 64);
    v += __shfl_xor(v, 32, 64);
    if (qd == 0)
      atomicAdd(&cs[n0 + wn * 64 + j * 16 + tq], v);
  }
}

// -------- transpose V [l][dv] -> V' [dv][l], scaled by 1/colsum[l] --------
__global__ __launch_bounds__(256) void tvscale(
    const unsigned short* __restrict__ QKV, unsigned short* __restrict__ Vp,
    const float* __restrict__ colsum, int zbase)
{
  __shared__ unsigned short tile[64][72];
  const int z = blockIdx.z;
  const int g = zbase + z;
  const int b = g >> 3, h = g & 7;
  const unsigned short* S = QKV + (size_t)b * 3145728 + (size_t)(16 + h) * 131072;
  unsigned short* D = Vp + (size_t)g * 131072;
  const float* cs = colsum + (size_t)g * 1024;
  const int l0 = blockIdx.x * 64;   // 16 tiles
  const int d0 = blockIdx.y * 64;   // 2 tiles
  const int t = threadIdx.x;
  {
    const int r = t >> 4, c4 = (t & 15) * 4;
    for (int it = 0; it < 4; ++it) {
      const int rr = r + it * 16;
      const ushort4 v = *(const ushort4*)(S + (size_t)(l0 + rr) * 128 + d0 + c4);
      *(ushort4*)&tile[rr][c4] = v;
    }
  }
  __syncthreads();
  {
    const int cc = t >> 4, r4 = (t & 15) * 4;
    const float4 c4v = *(const float4*)(cs + l0 + r4);
    for (int it = 0; it < 4; ++it) {
      const int c = cc + it * 16;   // dv
      ushort4 o;
      o.x = f2bf(bf2f(tile[r4 + 0][c]) / c4v.x);
      o.y = f2bf(bf2f(tile[r4 + 1][c]) / c4v.y);
      o.z = f2bf(bf2f(tile[r4 + 2][c]) / c4v.z);
      o.w = f2bf(bf2f(tile[r4 + 3][c]) / c4v.w);
      *(ushort4*)(D + (size_t)(d0 + c) * 1024 + l0 + r4) = o;
    }
  }
}

extern "C" void kernel_launch(void* const* d_in, const int* in_sizes, int n_in,
                              void* d_out, int out_size, void* d_ws, size_t ws_size,
                              hipStream_t stream) {
  const float* x    = (const float*)d_in[0];   // [8,1024,1024]  (B,D,L)
  const float* mask = (const float*)d_in[1];   // [8,1024]
  const float* Wq   = (const float*)d_in[2];   // [8,1024,128]
  const float* Wk   = (const float*)d_in[3];
  const float* Wv   = (const float*)d_in[4];
  const float* Wo   = (const float*)d_in[5];   // [1024,1024]
  float* out = (float*)d_out;                  // [8,1024,1024]  (B,D,L)

  char* p = (char*)d_ws;
  unsigned short* xt    = (unsigned short*)p; p += 16777216;  // [b][l][d] bf16
  unsigned short* WqkvT = (unsigned short*)p; p += 6291456;   // [24 heads][128][1024]
  unsigned short* Wot   = (unsigned short*)p; p += 2097152;   // [j][i]
  unsigned short* QKV   = (unsigned short*)p; p += 50331648;  // [b][24h][l][128]
  unsigned short* Vp    = (unsigned short*)p; p += 16777216;  // [b][h][dv][k]
  unsigned short* Hp    = (unsigned short*)p; p += 16777216;  // [b][l][h*128+dv]
  float* colsum = (float*)p; p += 262144;                     // [64][1024] fp32
  const size_t fixedBytes = (size_t)(p - (char*)d_ws);

  long nbh = 1;
  if (ws_size > fixedBytes) {
    nbh = (long)((ws_size - fixedBytes) / 2097152);
    if (nbh < 1) nbh = 1;
    if (nbh > 64) nbh = 64;
  }
  unsigned short* Ep = (unsigned short*)p;   // nbh x [q][k] bf16 (unnormalized exp)

  hipMemsetAsync(colsum, 0, 262144, stream);

  // prologue: transposes (2 dispatches instead of 5)
  transpose_x_wo<<<dim3(16, 16, 9), 256, 0, stream>>>(x, Wo, xt, Wot);
  transpose_w24<<<dim3(2, 16, 24), 256, 0, stream>>>(Wq, Wk, Wv, WqkvT);

  // QKV[b][gh][l][dk] = xt[b] * WqkvT[gh]^T   (z=192: gb=b, gh=0..23; 1536 blocks)
  gemm_tn<false><<<dim3(1, 8, 192), 256, 0, stream>>>(
      xt, WqkvT, (void*)QKV, 1024, 1024, 1024, 128, 1.f,
      0L, 1048576L, 0L,  0L, 0L, 131072L,  0L, 3145728L, 131072L, 0, 24);

  for (int s0 = 0; s0 < 64; s0 += (int)nbh) {
    const int cnt = (int)(((64 - s0) < nbh) ? (64 - s0) : nbh);
    // E + colsum (round-2 structure)
    gemm_scores_fused<<<dim3(8, 8, cnt), 256, 0, stream>>>(QKV, Ep, colsum, mask, s0);
    // V' = V^T / colsum (transpose fused with normalization)
    tvscale<<<dim3(16, 2, cnt), 256, 0, stream>>>(QKV, Vp, colsum, s0);
    // H[b][q][h*128+dv] = E[q,:] . V'[dv,:]   (M=1024 q, N=128 dv, K=1024 k)
    gemm_tn<false><<<dim3(1, 8, cnt), 256, 0, stream>>>(
        Ep, Vp, (void*)Hp, 1024, 1024, 1024, 1024, 1.f,
        1048576L, 0L, 0L,  0L, 1048576L, 131072L,  0L, 1048576L, 128L, s0, 8);
  }
  // out[b][j][l] = Wot[j,:] . H[b][l,:]   (M=1024 j, N=1024 l, K=1024 i)
  gemm_tn<true><<<dim3(8, 8, 8), 256, 0, stream>>>(
      Wot, Hp, (void*)out, 1024, 1024, 1024, 1024, 1.f,
      0L, 0L, 0L,  0L, 1048576L, 0L,  0L, 1048576L, 0L, 0, 1);
}